// Round 6
// baseline (408.415 us; speedup 1.0000x reference)
//
#include <hip/hip_runtime.h>
#include <cfloat>
#include <stdint.h>

#define P_TOT     4194304      // 8*512*1024 pixels
#define HW_       524288       // 512*1024
#define NCLS      19
#define IGNORE_IDX 255
#define MIN_KEPT_ 100000
#define THR       0.7f
#define L2E       1.44269504088896340736f
#define LN2       0.69314718055994530942f

#define SEG_PX    4096         // pixels per block (8 px/thread @ 512 threads)
#define NSEG      1024         // 1024 * 4096 = P_TOT

typedef float f32x4 __attribute__((ext_vector_type(4)));
typedef int   i32x4 __attribute__((ext_vector_type(4)));

// Non-temporal loads: zero-reuse streams; bypassing L2 allocation lifted the
// ~3.0 TB/s policy wall to 3.57 TB/s in R5.
__device__ __forceinline__ f32x4 ntload4(const float* p){
  return __builtin_nontemporal_load((const f32x4*)p);
}
__device__ __forceinline__ i32x4 ntload4i(const int* p){
  return __builtin_nontemporal_load((const i32x4*)p);
}

__device__ __forceinline__ double wred_d(double v){
  #pragma unroll
  for (int o = 32; o > 0; o >>= 1) v += __shfl_down(v, o, 64);
  return v;
}
__device__ __forceinline__ unsigned wred_u(unsigned v){
  #pragma unroll
  for (int o = 32; o > 0; o >>= 1) v += __shfl_down(v, o, 64);
  return v;
}

// Pass 1: class-OUTER sweep, online-softmax state in registers.
// R6: R4's 4-deep statically-rotated register pipeline + R5's nt loads.
// Mechanism: without nt, BW was capped by L2 allocation policy (~3.0 TB/s)
// so pipeline depth was irrelevant (R4 == R3 == R1). With nt (R5: 3.57 TB/s)
// loads see raw ~900cy HBM latency and no L2 buffering, so the serial
// load-drain-compute structure may now bind. This tests the two levers
// TOGETHER: 3 class-pairs (12 KB/wave) outstanding during every compute
// window, all through the nt path.
__global__ __launch_bounds__(512, 2) void ohem_pass1(
    const float* __restrict__ logits, const int* __restrict__ tgt,
    double* __restrict__ p_sle, double* __restrict__ p_sva,
    unsigned* __restrict__ p_cnt)
{
  const int t   = threadIdx.x;
  const int seg = blockIdx.x * SEG_PX;       // segment never crosses an image
  const int n   = seg >> 19;
  const int r0  = seg & (HW_ - 1);
  const float* plane0 = logits + (size_t)n * (NCLS * (size_t)HW_) + r0;

  int   lab[8];
  float m[8], s[8], g[8];

  #pragma unroll
  for (int j = 0; j < 2; j++){
    i32x4 tl = ntload4i(tgt + seg + j * 2048 + t * 4);
    lab[4*j+0] = tl.x; lab[4*j+1] = tl.y; lab[4*j+2] = tl.z; lab[4*j+3] = tl.w;
  }

  // class 0 initializes the online state
  #pragma unroll
  for (int j = 0; j < 2; j++){
    f32x4 v = ntload4(plane0 + j * 2048 + t * 4);
    #pragma unroll
    for (int k = 0; k < 4; k++){
      int p = 4*j + k;
      m[p] = v[k]; s[p] = 1.0f;
      g[p] = (lab[p] == 0) ? v[k] : 0.0f;
    }
  }

  // 4 rotating buffers; each holds one class PAIR:
  // B[0],B[1] = plane c (j=0,1);  B[2],B[3] = plane c+1 (j=0,1)
  f32x4 b0[4], b1[4], b2[4], b3[4];

#define LOADP(B, C) do {                                                 \
    const float* _pA = plane0 + (size_t)(C) * HW_;                       \
    B[0] = ntload4(_pA + t * 4);                                         \
    B[1] = ntload4(_pA + 2048 + t * 4);                                  \
    B[2] = ntload4(_pA + HW_ + t * 4);                                   \
    B[3] = ntload4(_pA + HW_ + 2048 + t * 4);                            \
  } while(0)

#define COMP(B, C) do {                                                  \
    _Pragma("unroll")                                                    \
    for (int j = 0; j < 2; j++){                                         \
      _Pragma("unroll")                                                  \
      for (int k = 0; k < 4; k++){                                       \
        int p = 4*j + k;                                                 \
        float x = B[j][k], y = B[2+j][k];                                \
        float mo = m[p];                                                 \
        float mn = fmaxf(mo, fmaxf(x, y));                               \
        float tt = mn * L2E;                                             \
        s[p] = s[p] * __builtin_amdgcn_exp2f(fmaf(mo, L2E, -tt))         \
             + __builtin_amdgcn_exp2f(fmaf(x, L2E, -tt))                 \
             + __builtin_amdgcn_exp2f(fmaf(y, L2E, -tt));                \
        m[p] = mn;                                                       \
        g[p] = (lab[p] == (C))     ? x : g[p];                           \
        g[p] = (lab[p] == (C) + 1) ? y : g[p];                           \
      }                                                                  \
    }                                                                    \
  } while(0)

  // 9 pairs (1,2)..(17,18), 4-deep rotation: load for pair i+3 issues
  // alongside compute of pair i. Buffers statically named (rule: runtime-
  // indexed reg arrays go to scratch).
  LOADP(b0, 1);  LOADP(b1, 3);  LOADP(b2, 5);
  LOADP(b3, 7);   COMP(b0, 1);
  LOADP(b0, 9);   COMP(b1, 3);
  LOADP(b1, 11);  COMP(b2, 5);
  LOADP(b2, 13);  COMP(b3, 7);
  LOADP(b3, 15);  COMP(b0, 9);
  LOADP(b0, 17);  COMP(b1, 11);
  COMP(b2, 13);
  COMP(b3, 15);
  COMP(b0, 17);

#undef LOADP
#undef COMP

  double sle = 0.0, sva = 0.0; unsigned cnt = 0;  // lo16=valid, hi16=pred<=THR
  #pragma unroll
  for (int p = 0; p < 8; p++){
    float lp = (g[p] - m[p]) - __builtin_amdgcn_logf(s[p]) * LN2;
    float pd = __builtin_amdgcn_exp2f(lp * L2E);
    if (lab[p] != IGNORE_IDX){
      cnt += 1u; sva += (double)lp;
      if (pd <= THR){ cnt += 1u << 16; sle += (double)lp; }
    }
  }
  sle = wred_d(sle); sva = wred_d(sva); cnt = wred_u(cnt);

  __shared__ double  ld1[8], ld2[8];
  __shared__ unsigned lc[8];
  int wv = t >> 6, ln = t & 63;
  if (ln == 0){ ld1[wv] = sle; ld2[wv] = sva; lc[wv] = cnt; }
  __syncthreads();
  if (t == 0){
    double a = 0, b = 0; unsigned c2 = 0;
    for (int i = 0; i < 8; i++){ a += ld1[i]; b += ld2[i]; c2 += lc[i]; }
    p_sle[blockIdx.x] = a; p_sva[blockIdx.x] = b; p_cnt[blockIdx.x] = c2;
  }
}

// Finish: reduce partials, resolve the three OHEM cases.
// Cold fallback (exact bitwise radix-select of the kth-smallest pred) only
// runs when count(valid & pred<=0.7) < MIN_KEPT < num_valid — never for the
// bench distribution, but kept for full correctness.
__global__ __launch_bounds__(1024) void ohem_finish(
    const float* __restrict__ logits, const int* __restrict__ tgt,
    const double* __restrict__ p_sle, const double* __restrict__ p_sva,
    const unsigned* __restrict__ p_cnt,
    unsigned* __restrict__ keys, float* __restrict__ logp,
    float* __restrict__ out)
{
  __shared__ double  rs1[16], rs2[16];
  __shared__ unsigned rc1[16], rc2[16];
  __shared__ unsigned s_flag, s_prefix, s_rank;
  __shared__ unsigned s_hist[4096];

  int t = threadIdx.x;
  double sle = 0.0, sva = 0.0; unsigned cle = 0, cva = 0;
  for (int i = t; i < NSEG; i += 1024){
    sle += p_sle[i]; sva += p_sva[i];
    unsigned c = p_cnt[i];
    cva += c & 0xFFFFu; cle += c >> 16;
  }
  sle = wred_d(sle); sva = wred_d(sva);
  cle = wred_u(cle); cva = wred_u(cva);
  int wv = t >> 6, ln = t & 63;
  if (ln == 0){ rs1[wv] = sle; rs2[wv] = sva; rc1[wv] = cle; rc2[wv] = cva; }
  __syncthreads();
  if (t == 0){
    double S1 = 0, S2 = 0; unsigned C1 = 0, C2 = 0;
    for (int i = 0; i < 16; i++){ S1 += rs1[i]; S2 += rs2[i]; C1 += rc1[i]; C2 += rc2[i]; }
    unsigned flag;
    if (C2 <= MIN_KEPT_){                       // do_ohem false: keep all valid
      unsigned d = C2 > 1u ? C2 : 1u;
      out[0] = (float)(-S2 / (double)d);
      flag = 0;
    } else if (C1 >= MIN_KEPT_){                // kth <= 0.7 => threshold = 0.7
      out[0] = (float)(-S1 / (double)C1);
      flag = 0;
    } else flag = 1;                            // need exact kth (> 0.7)
    s_flag = flag;
  }
  __syncthreads();
  if (!s_flag) return;

  // ---------- cold fallback: exact selection ----------
  for (int p = t; p < P_TOT; p += 1024){
    int n = p >> 19; int r = p & (HW_ - 1);
    const float* bp = logits + (size_t)n * (NCLS * (size_t)HW_) + r;
    int lab = tgt[p];
    int lv  = (lab != IGNORE_IDX);
    int ls  = lv ? lab : 0;
    float mxv = -FLT_MAX, va[NCLS];
    #pragma unroll
    for (int c = 0; c < NCLS; c++){
      float x = bp[(size_t)c * HW_];
      va[c] = x; mxv = fmaxf(mxv, x);
    }
    float xlv = va[0];
    #pragma unroll
    for (int c = 1; c < NCLS; c++) if (c == ls) xlv = va[c];
    float sev = 0.f;
    #pragma unroll
    for (int c = 0; c < NCLS; c++) sev += __expf(va[c] - mxv);
    float lp = (xlv - mxv) - __logf(sev);
    float pd = __expf(lp);
    keys[p] = lv ? __float_as_uint(pd) : 0xFFFFFFFFu;
    logp[p] = lp;
  }
  __syncthreads();

  unsigned prefix = 0, rank = MIN_KEPT_;        // 1-indexed rank
  #pragma unroll
  for (int rd = 0; rd < 3; rd++){
    const int sh = (rd == 0) ? 20 : (rd == 1) ? 8 : 0;
    const int nb = (rd == 2) ? 8 : 12;
    const unsigned nbin = 1u << nb;
    for (unsigned i = t; i < nbin; i += 1024) s_hist[i] = 0;
    __syncthreads();
    for (int p = t; p < P_TOT; p += 1024){
      unsigned k = keys[p];
      unsigned hi = (rd == 0) ? 0u : (k >> (sh + nb));
      if (hi == prefix) atomicAdd(&s_hist[(k >> sh) & (nbin - 1)], 1u);
    }
    __syncthreads();
    if (t == 0){
      unsigned cum = 0, b = 0;
      for (; b < nbin - 1; b++){
        unsigned cc = s_hist[b];
        if (cum + cc >= rank) break;
        cum += cc;
      }
      s_prefix = (prefix << nb) | b;
      s_rank = rank - cum;
    }
    __syncthreads();
    prefix = s_prefix; rank = s_rank;
    __syncthreads();
  }
  unsigned kb = prefix;                         // bit pattern of kth-smallest pred

  double s = 0.0; unsigned c = 0;
  for (int p = t; p < P_TOT; p += 1024){
    unsigned k = keys[p];
    if (k <= kb){ c++; s += (double)logp[p]; }  // invalid keys (0xFFFFFFFF) excluded
  }
  s = wred_d(s); c = wred_u(c);
  if (ln == 0){ rs1[wv] = s; rc1[wv] = c; }
  __syncthreads();
  if (t == 0){
    double S = 0; unsigned CC = 0;
    for (int i = 0; i < 16; i++){ S += rs1[i]; CC += rc1[i]; }
    unsigned d = CC > 1u ? CC : 1u;
    out[0] = (float)(-S / (double)d);
  }
}

extern "C" void kernel_launch(void* const* d_in, const int* in_sizes, int n_in,
                              void* d_out, int out_size, void* d_ws, size_t ws_size,
                              hipStream_t stream)
{
  const float* logits = (const float*)d_in[0];
  const int*   tgt    = (const int*)d_in[1];
  float* out = (float*)d_out;

  // ws layout: partial sums (hot path) then fallback arrays (cold only)
  double*   p_sle = (double*)d_ws;
  double*   p_sva = p_sle + NSEG;
  unsigned* p_cnt = (unsigned*)(p_sva + NSEG);
  unsigned* keys  = p_cnt + NSEG;            // P_TOT uints (cold path only)
  float*    logp  = (float*)(keys + P_TOT); // P_TOT floats (cold path only)

  hipLaunchKernelGGL(ohem_pass1, dim3(NSEG), dim3(512), 0, stream,
                     logits, tgt, p_sle, p_sva, p_cnt);
  hipLaunchKernelGGL(ohem_finish, dim3(1), dim3(1024), 0, stream,
                     logits, tgt, p_sle, p_sva, p_cnt, keys, logp, out);
}

// Round 7
// 400.685 us; speedup vs baseline: 1.0193x; 1.0193x over previous
//
#include <hip/hip_runtime.h>
#include <cfloat>
#include <stdint.h>

#define P_TOT     4194304      // 8*512*1024 pixels
#define HW_       524288       // 512*1024
#define NCLS      19
#define IGNORE_IDX 255
#define MIN_KEPT_ 100000
#define THR       0.7f
#define L2E       1.44269504088896340736f
#define LN2       0.69314718055994530942f

#define SEG_PX    8192         // pixels per block
#define NSEG      512          // 512 * 8192 = P_TOT

typedef float f32x4 __attribute__((ext_vector_type(4)));

// Non-temporal 16B load: logits are a zero-reuse 318 MB stream; nt bypasses
// L2 allocation. Lifted the ~3.0 TB/s L2-policy wall to 3.57 TB/s (R5);
// best of 7 structural variants. Pipeline depth refuted both with and
// without nt (R3/R4/R6).
__device__ __forceinline__ f32x4 ntload4(const float* p){
  return __builtin_nontemporal_load((const f32x4*)p);
}

__device__ __forceinline__ double wred_d(double v){
  #pragma unroll
  for (int o = 32; o > 0; o >>= 1) v += __shfl_down(v, o, 64);
  return v;
}
__device__ __forceinline__ unsigned wred_u(unsigned v){
  #pragma unroll
  for (int o = 32; o > 0; o >>= 1) v += __shfl_down(v, o, 64);
  return v;
}

// Pass 1: class-OUTER sweep with online-softmax state in registers.
// Best-measured structure: 16 px/thread, 32 KB linear runs per plane,
// no prefetch (TLP from 8 waves/block covers nt-load latency), nt loads.
// pass1 ~94 µs = 3.57 TB/s read-only.
__global__ __launch_bounds__(512) void ohem_pass1(
    const float* __restrict__ logits, const int* __restrict__ tgt,
    double* __restrict__ p_sle, double* __restrict__ p_sva,
    unsigned* __restrict__ p_cnt)
{
  const int t   = threadIdx.x;
  const int seg = blockIdx.x * SEG_PX;       // segment never crosses an image
  const int n   = seg >> 19;
  const int r0  = seg & (HW_ - 1);
  const float* plane0 = logits + (size_t)n * (NCLS * (size_t)HW_) + r0;

  int   lab[16];
  float m[16], s[16], g[16];

  #pragma unroll
  for (int j = 0; j < 4; j++){
    int4 tl = *(const int4*)(tgt + seg + j * 2048 + t * 4);
    lab[4*j+0] = tl.x; lab[4*j+1] = tl.y; lab[4*j+2] = tl.z; lab[4*j+3] = tl.w;
  }

  // class 0 initializes the online state
  #pragma unroll
  for (int j = 0; j < 4; j++){
    f32x4 v = ntload4(plane0 + j * 2048 + t * 4);
    #pragma unroll
    for (int k = 0; k < 4; k++){
      int p = 4*j + k;
      m[p] = v[k]; s[p] = 1.0f;
      g[p] = (lab[p] == 0) ? v[k] : 0.0f;
    }
  }

  // classes 1..18 as 9 pairs: one rescale exp per 2 classes
  #pragma unroll 1
  for (int c = 1; c < NCLS; c += 2){
    const float* pA = plane0 + (size_t)c * HW_;
    const float* pB = pA + HW_;
    f32x4 va[4], vb[4];
    #pragma unroll
    for (int j = 0; j < 4; j++){
      va[j] = ntload4(pA + j * 2048 + t * 4);
      vb[j] = ntload4(pB + j * 2048 + t * 4);
    }
    #pragma unroll
    for (int j = 0; j < 4; j++){
      #pragma unroll
      for (int k = 0; k < 4; k++){
        int p = 4*j + k;
        float x = va[j][k], y = vb[j][k];
        float mo = m[p];
        float mn = fmaxf(mo, fmaxf(x, y));
        float tt = mn * L2E;
        s[p] = s[p] * __builtin_amdgcn_exp2f(fmaf(mo, L2E, -tt))
             + __builtin_amdgcn_exp2f(fmaf(x, L2E, -tt))
             + __builtin_amdgcn_exp2f(fmaf(y, L2E, -tt));
        m[p] = mn;
        g[p] = (lab[p] == c)     ? x : g[p];
        g[p] = (lab[p] == c + 1) ? y : g[p];
      }
    }
  }

  double sle = 0.0, sva = 0.0; unsigned cnt = 0;  // lo16=valid, hi16=pred<=THR
  #pragma unroll
  for (int p = 0; p < 16; p++){
    float lp = (g[p] - m[p]) - __builtin_amdgcn_logf(s[p]) * LN2;
    float pd = __builtin_amdgcn_exp2f(lp * L2E);
    if (lab[p] != IGNORE_IDX){
      cnt += 1u; sva += (double)lp;
      if (pd <= THR){ cnt += 1u << 16; sle += (double)lp; }
    }
  }
  sle = wred_d(sle); sva = wred_d(sva); cnt = wred_u(cnt);

  __shared__ double  ld1[8], ld2[8];
  __shared__ unsigned lc[8];
  int wv = t >> 6, ln = t & 63;
  if (ln == 0){ ld1[wv] = sle; ld2[wv] = sva; lc[wv] = cnt; }
  __syncthreads();
  if (t == 0){
    double a = 0, b = 0; unsigned c2 = 0;
    for (int i = 0; i < 8; i++){ a += ld1[i]; b += ld2[i]; c2 += lc[i]; }
    p_sle[blockIdx.x] = a; p_sva[blockIdx.x] = b; p_cnt[blockIdx.x] = c2;
  }
}

// Finish: reduce partials, resolve the three OHEM cases.
// Cold fallback (exact bitwise radix-select of the kth-smallest pred) only
// runs when count(valid & pred<=0.7) < MIN_KEPT < num_valid — never for the
// bench distribution, but kept for full correctness.
__global__ __launch_bounds__(1024) void ohem_finish(
    const float* __restrict__ logits, const int* __restrict__ tgt,
    const double* __restrict__ p_sle, const double* __restrict__ p_sva,
    const unsigned* __restrict__ p_cnt,
    unsigned* __restrict__ keys, float* __restrict__ logp,
    float* __restrict__ out)
{
  __shared__ double  rs1[16], rs2[16];
  __shared__ unsigned rc1[16], rc2[16];
  __shared__ unsigned s_flag, s_prefix, s_rank;
  __shared__ unsigned s_hist[4096];

  int t = threadIdx.x;
  double sle = 0.0, sva = 0.0; unsigned cle = 0, cva = 0;
  for (int i = t; i < NSEG; i += 1024){
    sle += p_sle[i]; sva += p_sva[i];
    unsigned c = p_cnt[i];
    cva += c & 0xFFFFu; cle += c >> 16;
  }
  sle = wred_d(sle); sva = wred_d(sva);
  cle = wred_u(cle); cva = wred_u(cva);
  int wv = t >> 6, ln = t & 63;
  if (ln == 0){ rs1[wv] = sle; rs2[wv] = sva; rc1[wv] = cle; rc2[wv] = cva; }
  __syncthreads();
  if (t == 0){
    double S1 = 0, S2 = 0; unsigned C1 = 0, C2 = 0;
    for (int i = 0; i < 16; i++){ S1 += rs1[i]; S2 += rs2[i]; C1 += rc1[i]; C2 += rc2[i]; }
    unsigned flag;
    if (C2 <= MIN_KEPT_){                       // do_ohem false: keep all valid
      unsigned d = C2 > 1u ? C2 : 1u;
      out[0] = (float)(-S2 / (double)d);
      flag = 0;
    } else if (C1 >= MIN_KEPT_){                // kth <= 0.7 => threshold = 0.7
      out[0] = (float)(-S1 / (double)C1);
      flag = 0;
    } else flag = 1;                            // need exact kth (> 0.7)
    s_flag = flag;
  }
  __syncthreads();
  if (!s_flag) return;

  // ---------- cold fallback: exact selection ----------
  for (int p = t; p < P_TOT; p += 1024){
    int n = p >> 19; int r = p & (HW_ - 1);
    const float* bp = logits + (size_t)n * (NCLS * (size_t)HW_) + r;
    int lab = tgt[p];
    int lv  = (lab != IGNORE_IDX);
    int ls  = lv ? lab : 0;
    float mxv = -FLT_MAX, va[NCLS];
    #pragma unroll
    for (int c = 0; c < NCLS; c++){
      float x = bp[(size_t)c * HW_];
      va[c] = x; mxv = fmaxf(mxv, x);
    }
    float xlv = va[0];
    #pragma unroll
    for (int c = 1; c < NCLS; c++) if (c == ls) xlv = va[c];
    float sev = 0.f;
    #pragma unroll
    for (int c = 0; c < NCLS; c++) sev += __expf(va[c] - mxv);
    float lp = (xlv - mxv) - __logf(sev);
    float pd = __expf(lp);
    keys[p] = lv ? __float_as_uint(pd) : 0xFFFFFFFFu;
    logp[p] = lp;
  }
  __syncthreads();

  unsigned prefix = 0, rank = MIN_KEPT_;        // 1-indexed rank
  #pragma unroll
  for (int rd = 0; rd < 3; rd++){
    const int sh = (rd == 0) ? 20 : (rd == 1) ? 8 : 0;
    const int nb = (rd == 2) ? 8 : 12;
    const unsigned nbin = 1u << nb;
    for (unsigned i = t; i < nbin; i += 1024) s_hist[i] = 0;
    __syncthreads();
    for (int p = t; p < P_TOT; p += 1024){
      unsigned k = keys[p];
      unsigned hi = (rd == 0) ? 0u : (k >> (sh + nb));
      if (hi == prefix) atomicAdd(&s_hist[(k >> sh) & (nbin - 1)], 1u);
    }
    __syncthreads();
    if (t == 0){
      unsigned cum = 0, b = 0;
      for (; b < nbin - 1; b++){
        unsigned cc = s_hist[b];
        if (cum + cc >= rank) break;
        cum += cc;
      }
      s_prefix = (prefix << nb) | b;
      s_rank = rank - cum;
    }
    __syncthreads();
    prefix = s_prefix; rank = s_rank;
    __syncthreads();
  }
  unsigned kb = prefix;                         // bit pattern of kth-smallest pred

  double s = 0.0; unsigned c = 0;
  for (int p = t; p < P_TOT; p += 1024){
    unsigned k = keys[p];
    if (k <= kb){ c++; s += (double)logp[p]; }  // invalid keys (0xFFFFFFFF) excluded
  }
  s = wred_d(s); c = wred_u(c);
  if (ln == 0){ rs1[wv] = s; rc1[wv] = c; }
  __syncthreads();
  if (t == 0){
    double S = 0; unsigned CC = 0;
    for (int i = 0; i < 16; i++){ S += rs1[i]; CC += rc1[i]; }
    unsigned d = CC > 1u ? CC : 1u;
    out[0] = (float)(-S / (double)d);
  }
}

extern "C" void kernel_launch(void* const* d_in, const int* in_sizes, int n_in,
                              void* d_out, int out_size, void* d_ws, size_t ws_size,
                              hipStream_t stream)
{
  const float* logits = (const float*)d_in[0];
  const int*   tgt    = (const int*)d_in[1];
  float* out = (float*)d_out;

  // ws layout: partial sums (hot path) then fallback arrays (cold only)
  double*   p_sle = (double*)d_ws;
  double*   p_sva = p_sle + NSEG;
  unsigned* p_cnt = (unsigned*)(p_sva + NSEG);
  unsigned* keys  = p_cnt + NSEG;            // P_TOT uints (cold path only)
  float*    logp  = (float*)(keys + P_TOT); // P_TOT floats (cold path only)

  hipLaunchKernelGGL(ohem_pass1, dim3(NSEG), dim3(512), 0, stream,
                     logits, tgt, p_sle, p_sva, p_cnt);
  hipLaunchKernelGGL(ohem_finish, dim3(1), dim3(1024), 0, stream,
                     logits, tgt, p_sle, p_sva, p_cnt, keys, logp, out);
}